// Round 1
// 325.587 us; speedup vs baseline: 1.0469x; 1.0469x over previous
//
#include <hip/hip_runtime.h>

#define NN   50000
#define NE   800000
#define INF  128
#define EF   32
#define OUTF 128
#define KDIM 288   // 128 (h) + 128 (mean_h) + 32 (mean_e)
#define NBLK ((NN + 1023) / 1024)   // 49 scan blocks

typedef __attribute__((ext_vector_type(8))) short     short8;   // 8 bf16
typedef __attribute__((ext_vector_type(8))) unsigned short ushort8;
typedef __attribute__((ext_vector_type(4))) float     float4v;

__device__ __forceinline__ unsigned short f2bf(float f) {
    union { float f; unsigned int u; } c; c.f = f;
    const unsigned int r = (c.u + 0x7FFFu + ((c.u >> 16) & 1u)) >> 16;
    return (unsigned short)r;
}

// ---------------------------------------------------------------------------
// Prep: build fused matrix M (288x128) fp32 and bias vector c (128).
//   rows 0..127   : M[f][j]     = W_w[j][f]                         (h_dst)
//   rows 128..287 : M[128+m][j] = sum_k weight[m][k]*W_w[j][128+k]  (h_neigh)
//   c[j] = W_b[j] + bias[j]
// ---------------------------------------------------------------------------
__global__ void prep_kernel(const float* __restrict__ weight,
                            const float* __restrict__ W_w,
                            const float* __restrict__ W_b,
                            const float* __restrict__ bias,
                            float* __restrict__ Mmat,
                            float* __restrict__ cvec) {
    __shared__ float wrow[OUTF];
    const int r = blockIdx.x;
    const int j = threadIdx.x;
    if (r < 128) {
        Mmat[r * OUTF + j] = W_w[j * 256 + r];
        return;
    }
    if (r == KDIM) {
        cvec[j] = W_b[j] + bias[j];
        return;
    }
    const int m = r - 128;
    wrow[j] = weight[m * OUTF + j];
    __syncthreads();
    float acc = 0.f;
#pragma unroll 8
    for (int k = 0; k < OUTF; ++k)
        acc += wrow[k] * W_w[j * 256 + 128 + k];
    Mmat[r * OUTF + j] = acc;
}

// ---------------------------------------------------------------------------
// Pack M into bf16 MFMA B-fragment order: Mb[kb(9)][ct(8)][lane(64)][8].
// ---------------------------------------------------------------------------
__global__ void pack_kernel(const float* __restrict__ Mmat,
                            unsigned short* __restrict__ Mb) {
    const int b = blockIdx.x;          // kb*8 + ct
    const int kb = b >> 3;
    const int ct = b & 7;
    const int lane = threadIdx.x;
    const int col = ct * 16 + (lane & 15);
    const int k0 = kb * 32 + (lane >> 4) * 8;
    ushort8 v;
#pragma unroll
    for (int i = 0; i < 8; ++i)
        v[i] = f2bf(Mmat[(size_t)(k0 + i) * OUTF + col]);
    *(ushort8*)(Mb + ((size_t)(b * 64 + lane) * 8)) = v;
}

// ---------------------------------------------------------------------------
// h fp32 -> bf16 table (one-time stream). 6.4M elems / 8 per thread.
// ---------------------------------------------------------------------------
__global__ __launch_bounds__(256)
void cvt_h_kernel(const float* __restrict__ h, unsigned short* __restrict__ hb) {
    const size_t i = (size_t)(blockIdx.x * 256 + threadIdx.x) * 8;
    const float4 a = *(const float4*)(h + i);
    const float4 b = *(const float4*)(h + i + 4);
    ushort8 v;
    v[0] = f2bf(a.x); v[1] = f2bf(a.y); v[2] = f2bf(a.z); v[3] = f2bf(a.w);
    v[4] = f2bf(b.x); v[5] = f2bf(b.y); v[6] = f2bf(b.z); v[7] = f2bf(b.w);
    *(ushort8*)(hb + i) = v;
}

// ---------------------------------------------------------------------------
// CSR build step 1: histogram of dst into off[0..NN-1] (pre-zeroed)
// ---------------------------------------------------------------------------
__global__ __launch_bounds__(256)
void hist_kernel(const int* __restrict__ dst, int* __restrict__ off) {
    const int e = (blockIdx.x * 256 + threadIdx.x) * 4;
    if (e < NE) {
        const int4 d = *(const int4*)(dst + e);
        atomicAdd(&off[d.x], 1);
        atomicAdd(&off[d.y], 1);
        atomicAdd(&off[d.z], 1);
        atomicAdd(&off[d.w], 1);
    }
}

// ---------------------------------------------------------------------------
// Scan phase 1: per-block (1024 elems) sum -> partial[b]
// ---------------------------------------------------------------------------
__global__ __launch_bounds__(256)
void scan1_kernel(const int* __restrict__ off, int* __restrict__ partial) {
    const int b = blockIdx.x;
    const int tid = threadIdx.x;
    const int idx = b * 1024 + tid * 4;
    int v0 = 0, v1 = 0, v2 = 0, v3 = 0;
    if (idx + 3 < NN) {
        const int4 q = *(const int4*)(off + idx);
        v0 = q.x; v1 = q.y; v2 = q.z; v3 = q.w;
    } else {
        if (idx + 0 < NN) v0 = off[idx + 0];
        if (idx + 1 < NN) v1 = off[idx + 1];
        if (idx + 2 < NN) v2 = off[idx + 2];
    }
    int t = v0 + v1 + v2 + v3;
#pragma unroll
    for (int ofs = 32; ofs > 0; ofs >>= 1) t += __shfl_down(t, ofs);
    __shared__ int wsum[4];
    if ((tid & 63) == 0) wsum[tid >> 6] = t;
    __syncthreads();
    if (tid == 0) partial[b] = wsum[0] + wsum[1] + wsum[2] + wsum[3];
}

// ---------------------------------------------------------------------------
// Scan phase 2+3 fused: every block re-scans the 49 partials in one wave,
// then does its local exclusive scan + rewrite of off.
// ---------------------------------------------------------------------------
__global__ __launch_bounds__(256)
void scan3_kernel(int* __restrict__ off, const int* __restrict__ partial) {
    __shared__ int blockbase;
    __shared__ int wsum[4];
    const int b = blockIdx.x;
    const int tid = threadIdx.x;
    const int lane = tid & 63;
    const int wid = tid >> 6;

    if (wid == 0) {
        const int v = (lane < NBLK) ? partial[lane] : 0;
        int x = v;
#pragma unroll
        for (int ofs = 1; ofs < 64; ofs <<= 1) {
            const int t = __shfl_up(x, ofs);
            if (lane >= ofs) x += t;
        }
        if (lane == b) blockbase = x - v;   // exclusive prefix of this block
    }

    const int idx = b * 1024 + tid * 4;
    int v0 = 0, v1 = 0, v2 = 0, v3 = 0;
    if (idx + 3 < NN) {
        const int4 q = *(const int4*)(off + idx);
        v0 = q.x; v1 = q.y; v2 = q.z; v3 = q.w;
    } else {
        if (idx + 0 < NN) v0 = off[idx + 0];
        if (idx + 1 < NN) v1 = off[idx + 1];
        if (idx + 2 < NN) v2 = off[idx + 2];
    }
    const int tsum = v0 + v1 + v2 + v3;
    int x = tsum;
#pragma unroll
    for (int ofs = 1; ofs < 64; ofs <<= 1) {
        const int t = __shfl_up(x, ofs);
        if (lane >= ofs) x += t;
    }
    if (lane == 63) wsum[wid] = x;
    __syncthreads();
    int wp = 0;
    for (int w = 0; w < wid; ++w) wp += wsum[w];
    const int base = blockbase + wp + (x - tsum);
    if (idx + 0 < NN) off[idx + 0] = base;
    if (idx + 1 < NN) off[idx + 1] = base + v0;
    if (idx + 2 < NN) off[idx + 2] = base + v0 + v1;
    if (idx + 3 < NN) off[idx + 3] = base + v0 + v1 + v2;
}

// ---------------------------------------------------------------------------
// CSR build step 3: scatter {src,edge} pairs. Cursor trick: afterwards
// off[d] == end offset of segment d (start = off[d-1]).
// ---------------------------------------------------------------------------
__global__ __launch_bounds__(256)
void scatter_ids_kernel(const int* __restrict__ srcv,
                        const int* __restrict__ dst,
                        int* __restrict__ off,
                        int2* __restrict__ eo2) {
    const int e = (blockIdx.x * 256 + threadIdx.x) * 4;
    if (e < NE) {
        const int4 s = *(const int4*)(srcv + e);
        const int4 d = *(const int4*)(dst + e);
        int p;
        p = atomicAdd(&off[d.x], 1); eo2[p] = make_int2(s.x, e + 0);
        p = atomicAdd(&off[d.y], 1); eo2[p] = make_int2(s.y, e + 1);
        p = atomicAdd(&off[d.z], 1); eo2[p] = make_int2(s.z, e + 2);
        p = atomicAdd(&off[d.w], 1); eo2[p] = make_int2(s.w, e + 3);
    }
}

// ---------------------------------------------------------------------------
// Gather: one wave per node; readlane-broadcast indices; unroll-8 h rows.
// h is read from the bf16 table (256 B/row instead of 512) and the means are
// written directly in bf16 (bit-identical to the f2bf the GEMM applied).
// eo2/eftr are once-only streams -> nontemporal loads.
// ---------------------------------------------------------------------------
__global__ __launch_bounds__(256)
void gather_kernel(const unsigned short* __restrict__ hb,
                   const float* __restrict__ eftr,
                   const int* __restrict__ off,   // end offsets
                   const int2* __restrict__ eo2,
                   unsigned short* __restrict__ mean_h,
                   unsigned short* __restrict__ mean_e) {
    const int tid = threadIdx.x;
    const int lane = tid & 63;
    const int node = blockIdx.x * 4 + (tid >> 6);
    if (node >= NN) return;

    const int end = off[node];
    const int start = (node == 0) ? 0 : off[node - 1];

    float ax = 0.f, ay = 0.f, ae = 0.f;
    const unsigned short* hcol = hb + lane * 2;   // lane covers cols 2l,2l+1
    const int el = lane & 31;
    const bool lowhalf = (lane < 32);

    for (int base = start; base < end; base += 64) {
        const int m = min(64, end - base);
        int px = 0, py = 0;
        if (base + lane < end) {
            const long long pv =
                __builtin_nontemporal_load((const long long*)(eo2 + base + lane));
            px = (int)pv;
            py = (int)(pv >> 32);
        }
        int j = 0;
        for (; j + 7 < m; j += 8) {
            int s[8], e[8];
#pragma unroll
            for (int u = 0; u < 8; ++u) {
                s[u] = __builtin_amdgcn_readlane(px, j + u);
                e[u] = __builtin_amdgcn_readlane(py, j + u);
            }
            unsigned v[8];
#pragma unroll
            for (int u = 0; u < 8; ++u)
                v[u] = *(const unsigned*)(hcol + (size_t)s[u] * INF);
            float f[4];
#pragma unroll
            for (int u = 0; u < 4; ++u) {
                const int ee = lowhalf ? e[2 * u] : e[2 * u + 1];
                f[u] = __builtin_nontemporal_load(&eftr[(size_t)ee * EF + el]);
            }
#pragma unroll
            for (int u = 0; u < 8; ++u) {
                union { unsigned u; float f; } lo, hi;
                lo.u = v[u] << 16;
                hi.u = v[u] & 0xffff0000u;
                ax += lo.f; ay += hi.f;
            }
            ae += (f[0] + f[1]) + (f[2] + f[3]);
        }
        for (; j < m; ++j) {
            const int s0 = __builtin_amdgcn_readlane(px, j);
            const int e0 = __builtin_amdgcn_readlane(py, j);
            const unsigned v0 = *(const unsigned*)(hcol + (size_t)s0 * INF);
            union { unsigned u; float f; } lo, hi;
            lo.u = v0 << 16;
            hi.u = v0 & 0xffff0000u;
            ax += lo.f; ay += hi.f;
            if (lowhalf) ae += __builtin_nontemporal_load(&eftr[(size_t)e0 * EF + el]);
        }
    }

    ae += __shfl(ae, lane + 32);   // fold odd-edge half into low half

    const float inv = 1.f / fmaxf((float)(end - start), 1.f);
    const unsigned mx = f2bf(ax * inv);
    const unsigned my = f2bf(ay * inv);
    *(unsigned*)(mean_h + (size_t)node * INF + lane * 2) = mx | (my << 16);
    if (lowhalf) mean_e[(size_t)node * EF + el] = f2bf(ae * inv);
}

// ---------------------------------------------------------------------------
// Node GEMM via MFMA (bf16 in, fp32 acc). LDS-free, barrier-free.
// A operands now load directly as bf16 ushort8 (no cvt chain).
// ---------------------------------------------------------------------------
__global__ __launch_bounds__(256)
void node_gemm_kernel(const unsigned short* __restrict__ hb,
                      const unsigned short* __restrict__ mean_h,
                      const unsigned short* __restrict__ mean_e,
                      const unsigned short* __restrict__ Mb,
                      const float* __restrict__ cvec,
                      float* __restrict__ out) {
    const int tid = threadIdx.x;
    const int lane = tid & 63;
    const int wid = tid >> 6;
    const int nt = blockIdx.x * 4 + wid;     // 16-node tile id
    const int m16 = lane & 15;
    const int quad = lane >> 4;
    const int koff = quad * 8;

    const int anode = nt * 16 + m16;
    const int nclamp = (anode < NN) ? anode : (NN - 1);

    float4v acc[8] = {};

    for (int kb = 0; kb < 9; ++kb) {
        const unsigned short* srcp;
        if (kb < 4)
            srcp = hb + (size_t)nclamp * INF + kb * 32 + koff;
        else if (kb < 8)
            srcp = mean_h + (size_t)nclamp * INF + (kb - 4) * 32 + koff;
        else
            srcp = mean_e + (size_t)nclamp * EF + koff;
        const short8 a = *(const short8*)(const void*)srcp;

        const short8* bp = (const short8*)(Mb + (size_t)kb * 8 * 64 * 8);
#pragma unroll
        for (int ct = 0; ct < 8; ++ct) {
            const short8 b = bp[ct * 64 + lane];
            acc[ct] = __builtin_amdgcn_mfma_f32_16x16x32_bf16(a, b, acc[ct], 0, 0, 0);
        }
    }

    float cv[8];
#pragma unroll
    for (int ct = 0; ct < 8; ++ct) cv[ct] = cvec[ct * 16 + m16];

#pragma unroll
    for (int r = 0; r < 4; ++r) {
        const int nrow = nt * 16 + quad * 4 + r;
        if (nrow < NN) {
            float* orow = out + (size_t)nrow * OUTF;
#pragma unroll
            for (int ct = 0; ct < 8; ++ct)
                orow[ct * 16 + m16] = acc[ct][r] + cv[ct];
        }
    }
}

extern "C" void kernel_launch(void* const* d_in, const int* in_sizes, int n_in,
                              void* d_out, int out_size, void* d_ws, size_t ws_size,
                              hipStream_t stream) {
    const float* h      = (const float*)d_in[0];
    const float* eftr   = (const float*)d_in[1];
    const float* weight = (const float*)d_in[2];
    const float* W_w    = (const float*)d_in[3];
    const float* W_b    = (const float*)d_in[4];
    const float* bias   = (const float*)d_in[5];
    const int*   src    = (const int*)d_in[6];
    const int*   dst    = (const int*)d_in[7];
    float* out = (float*)d_out;

    // workspace layout (byte offsets, all 16B-aligned where needed):
    char* base = (char*)d_ws;
    unsigned short* mean_h = (unsigned short*)(base);                     // NN*128 bf16 = 12,800,000 B
    unsigned short* mean_e = (unsigned short*)(base + 12800000);          // NN*32  bf16 =  3,200,000 B
    unsigned short* h_bf   = (unsigned short*)(base + 16000000);          // NN*128 bf16 = 12,800,000 B
    float* Mmat            = (float*)(base + 28800000);                   // 288*128 f32 =    147,456 B
    float* cvec            = (float*)(base + 28947456);                   // 128 f32     =        512 B
    unsigned short* Mb     = (unsigned short*)(base + 28947968);          // 9*8*64*8 bf16 =   73,728 B
    int*   off             = (int*)(base + 29021696);                     // NN int      =    200,000 B
    int2*  eo2             = (int2*)(base + 29221696);                    // NE int2     =  6,400,000 B
    int*   partial         = (int*)(base + 35621696);                     // NBLK int
    // total ≈ 35.6 MB

    hipMemsetAsync(off, 0, (size_t)NN * sizeof(int), stream);

    prep_kernel<<<KDIM + 1, 128, 0, stream>>>(weight, W_w, W_b, bias, Mmat, cvec);
    pack_kernel<<<72, 64, 0, stream>>>(Mmat, Mb);
    cvt_h_kernel<<<3125, 256, 0, stream>>>(h, h_bf);
    hist_kernel<<<(NE / 4 + 255) / 256, 256, 0, stream>>>(dst, off);
    scan1_kernel<<<NBLK, 256, 0, stream>>>(off, partial);
    scan3_kernel<<<NBLK, 256, 0, stream>>>(off, partial);
    scatter_ids_kernel<<<(NE / 4 + 255) / 256, 256, 0, stream>>>(src, dst, off, eo2);
    gather_kernel<<<(NN + 3) / 4, 256, 0, stream>>>(h_bf, eftr, off, eo2,
                                                    mean_h, mean_e);
    node_gemm_kernel<<<(NN / 64) + 1, 256, 0, stream>>>(h_bf, mean_h, mean_e,
                                                        Mb, cvec, out);
}

// Round 3
// 324.088 us; speedup vs baseline: 1.0517x; 1.0046x over previous
//
#include <hip/hip_runtime.h>

#define NN   50000
#define NE   800000
#define INF  128
#define EF   32
#define OUTF 128
#define KDIM 288   // 128 (h) + 128 (mean_h) + 32 (mean_e)
#define NBLK ((NN + 1023) / 1024)   // 49 scan blocks
#define CVT_BLKS 3125               // NN*INF/2048 exactly

typedef __attribute__((ext_vector_type(8))) short     short8;   // 8 bf16
typedef __attribute__((ext_vector_type(8))) unsigned short ushort8;
typedef __attribute__((ext_vector_type(4))) float     float4v;
typedef __attribute__((ext_vector_type(2))) float     float2v;

__device__ __forceinline__ unsigned short f2bf(float f) {
    union { float f; unsigned int u; } c; c.f = f;
    const unsigned int r = (c.u + 0x7FFFu + ((c.u >> 16) & 1u)) >> 16;
    return (unsigned short)r;
}

// ---------------------------------------------------------------------------
// Prep: build fused matrix M (288x128) fp32 and bias vector c (128).
//   rows 0..127   : M[f][j]     = W_w[j][f]                         (h_dst)
//   rows 128..287 : M[128+m][j] = sum_k weight[m][k]*W_w[j][128+k]  (h_neigh)
//   c[j] = W_b[j] + bias[j]
// ---------------------------------------------------------------------------
__global__ void prep_kernel(const float* __restrict__ weight,
                            const float* __restrict__ W_w,
                            const float* __restrict__ W_b,
                            const float* __restrict__ bias,
                            float* __restrict__ Mmat,
                            float* __restrict__ cvec) {
    __shared__ float wrow[OUTF];
    const int r = blockIdx.x;
    const int j = threadIdx.x;
    if (r < 128) {
        Mmat[r * OUTF + j] = W_w[j * 256 + r];
        return;
    }
    if (r == KDIM) {
        cvec[j] = W_b[j] + bias[j];
        return;
    }
    const int m = r - 128;
    wrow[j] = weight[m * OUTF + j];
    __syncthreads();
    float acc = 0.f;
#pragma unroll 8
    for (int k = 0; k < OUTF; ++k)
        acc += wrow[k] * W_w[j * 256 + 128 + k];
    Mmat[r * OUTF + j] = acc;
}

// ---------------------------------------------------------------------------
// Pack M into bf16 MFMA B-fragment order: Mb[kb(9)][ct(8)][lane(64)][8].
// ---------------------------------------------------------------------------
__global__ void pack_kernel(const float* __restrict__ Mmat,
                            unsigned short* __restrict__ Mb) {
    const int b = blockIdx.x;          // kb*8 + ct
    const int kb = b >> 3;
    const int ct = b & 7;
    const int lane = threadIdx.x;
    const int col = ct * 16 + (lane & 15);
    const int k0 = kb * 32 + (lane >> 4) * 8;
    ushort8 v;
#pragma unroll
    for (int i = 0; i < 8; ++i)
        v[i] = f2bf(Mmat[(size_t)(k0 + i) * OUTF + col]);
    *(ushort8*)(Mb + ((size_t)(b * 64 + lane) * 8)) = v;
}

// ---------------------------------------------------------------------------
// Fused: h fp32->bf16 table (+ zero row NN) and dst histogram.
// Role split by blockIdx: [0,3125)=cvt, 3125=zero row, (3125,3908)=hist.
// ---------------------------------------------------------------------------
__global__ __launch_bounds__(256)
void cvt_hist_kernel(const float* __restrict__ h,
                     unsigned short* __restrict__ hb,
                     const int* __restrict__ dst,
                     int* __restrict__ off) {
    const int b = blockIdx.x;
    if (b < CVT_BLKS) {
        const size_t i = (size_t)(b * 256 + threadIdx.x) * 8;
        const float4 a0 = *(const float4*)(h + i);
        const float4 a1 = *(const float4*)(h + i + 4);
        ushort8 v;
        v[0] = f2bf(a0.x); v[1] = f2bf(a0.y); v[2] = f2bf(a0.z); v[3] = f2bf(a0.w);
        v[4] = f2bf(a1.x); v[5] = f2bf(a1.y); v[6] = f2bf(a1.z); v[7] = f2bf(a1.w);
        *(ushort8*)(hb + i) = v;
        return;
    }
    if (b == CVT_BLKS) {
        // zero row NN (used as target for masked-off edge slots in gather)
        if (threadIdx.x < 16) {
            ushort8 z = {};
            *(ushort8*)(hb + (size_t)NN * INF + threadIdx.x * 8) = z;
        }
        return;
    }
    const int e = ((b - CVT_BLKS - 1) * 256 + threadIdx.x) * 4;
    if (e < NE) {
        const int4 d = *(const int4*)(dst + e);
        atomicAdd(&off[d.x], 1);
        atomicAdd(&off[d.y], 1);
        atomicAdd(&off[d.z], 1);
        atomicAdd(&off[d.w], 1);
    }
}

// ---------------------------------------------------------------------------
// Scan phase 1: per-block (1024 elems) sum -> partial[b]
// ---------------------------------------------------------------------------
__global__ __launch_bounds__(256)
void scan1_kernel(const int* __restrict__ off, int* __restrict__ partial) {
    const int b = blockIdx.x;
    const int tid = threadIdx.x;
    const int idx = b * 1024 + tid * 4;
    int v0 = 0, v1 = 0, v2 = 0, v3 = 0;
    if (idx + 3 < NN) {
        const int4 q = *(const int4*)(off + idx);
        v0 = q.x; v1 = q.y; v2 = q.z; v3 = q.w;
    } else {
        if (idx + 0 < NN) v0 = off[idx + 0];
        if (idx + 1 < NN) v1 = off[idx + 1];
        if (idx + 2 < NN) v2 = off[idx + 2];
    }
    int t = v0 + v1 + v2 + v3;
#pragma unroll
    for (int ofs = 32; ofs > 0; ofs >>= 1) t += __shfl_down(t, ofs);
    __shared__ int wsum[4];
    if ((tid & 63) == 0) wsum[tid >> 6] = t;
    __syncthreads();
    if (tid == 0) partial[b] = wsum[0] + wsum[1] + wsum[2] + wsum[3];
}

// ---------------------------------------------------------------------------
// Scan phase 2+3 fused: every block re-scans the 49 partials in one wave,
// then does its local exclusive scan + rewrite of off.
// ---------------------------------------------------------------------------
__global__ __launch_bounds__(256)
void scan3_kernel(int* __restrict__ off, const int* __restrict__ partial) {
    __shared__ int blockbase;
    __shared__ int wsum[4];
    const int b = blockIdx.x;
    const int tid = threadIdx.x;
    const int lane = tid & 63;
    const int wid = tid >> 6;

    if (wid == 0) {
        const int v = (lane < NBLK) ? partial[lane] : 0;
        int x = v;
#pragma unroll
        for (int ofs = 1; ofs < 64; ofs <<= 1) {
            const int t = __shfl_up(x, ofs);
            if (lane >= ofs) x += t;
        }
        if (lane == b) blockbase = x - v;   // exclusive prefix of this block
    }

    const int idx = b * 1024 + tid * 4;
    int v0 = 0, v1 = 0, v2 = 0, v3 = 0;
    if (idx + 3 < NN) {
        const int4 q = *(const int4*)(off + idx);
        v0 = q.x; v1 = q.y; v2 = q.z; v3 = q.w;
    } else {
        if (idx + 0 < NN) v0 = off[idx + 0];
        if (idx + 1 < NN) v1 = off[idx + 1];
        if (idx + 2 < NN) v2 = off[idx + 2];
    }
    const int tsum = v0 + v1 + v2 + v3;
    int x = tsum;
#pragma unroll
    for (int ofs = 1; ofs < 64; ofs <<= 1) {
        const int t = __shfl_up(x, ofs);
        if (lane >= ofs) x += t;
    }
    if (lane == 63) wsum[wid] = x;
    __syncthreads();
    int wp = 0;
    for (int w = 0; w < wid; ++w) wp += wsum[w];
    const int base = blockbase + wp + (x - tsum);
    if (idx + 0 < NN) off[idx + 0] = base;
    if (idx + 1 < NN) off[idx + 1] = base + v0;
    if (idx + 2 < NN) off[idx + 2] = base + v0 + v1;
    if (idx + 3 < NN) off[idx + 3] = base + v0 + v1 + v2;
}

// ---------------------------------------------------------------------------
// CSR build step 3: scatter {src,edge} pairs. Cursor trick: afterwards
// off[d] == end offset of segment d (start = off[d-1]).
// ---------------------------------------------------------------------------
__global__ __launch_bounds__(256)
void scatter_ids_kernel(const int* __restrict__ srcv,
                        const int* __restrict__ dst,
                        int* __restrict__ off,
                        int2* __restrict__ eo2) {
    const int e = (blockIdx.x * 256 + threadIdx.x) * 4;
    if (e < NE) {
        const int4 s = *(const int4*)(srcv + e);
        const int4 d = *(const int4*)(dst + e);
        int p;
        p = atomicAdd(&off[d.x], 1); eo2[p] = make_int2(s.x, e + 0);
        p = atomicAdd(&off[d.y], 1); eo2[p] = make_int2(s.y, e + 1);
        p = atomicAdd(&off[d.z], 1); eo2[p] = make_int2(s.z, e + 2);
        p = atomicAdd(&off[d.w], 1); eo2[p] = make_int2(s.w, e + 3);
    }
}

// ---------------------------------------------------------------------------
// Gather: one wave per node. Wave is split into four 16-lane groups; each
// group reads one edge's FULL h row (16B/lane dwordx4 = 256B bf16 row) and
// one edge's full eftr row (8B/lane = 128B row). 4 edges per VMEM inst
// (3x fewer requests than the 1-edge/4B scheme). Indices distributed via
// ds_bpermute; tail slots are pointed at zero-row NN (h) / edge 0 with a
// masked addend (eftr). Per-group partials fold with 2 shfl_xor rounds.
// ---------------------------------------------------------------------------
__global__ __launch_bounds__(256)
void gather_kernel(const unsigned short* __restrict__ hb,
                   const float* __restrict__ eftr,
                   const int* __restrict__ off,   // end offsets
                   const int2* __restrict__ eo2,
                   unsigned short* __restrict__ mean_h,
                   unsigned short* __restrict__ mean_e) {
    const int tid = threadIdx.x;
    const int lane = tid & 63;
    const int node = blockIdx.x * 4 + (tid >> 6);
    if (node >= NN) return;

    const int end = off[node];
    const int start = (node == 0) ? 0 : off[node - 1];

    const int ql = lane & 15;      // position within 16-lane group
    const int qg = lane >> 4;      // edge-slot group 0..3

    float ax[8] = {0.f, 0.f, 0.f, 0.f, 0.f, 0.f, 0.f, 0.f};
    float aex = 0.f, aey = 0.f;

    for (int base = start; base < end; base += 64) {
        const int m = min(64, end - base);
        int px = 0, py = 0;
        if (lane < m) {
            const long long pv =
                __builtin_nontemporal_load((const long long*)(eo2 + base + lane));
            px = (int)pv;
            py = (int)(pv >> 32);
        }
        for (int j = 0; j < m; j += 8) {
#pragma unroll
            for (int u = 0; u < 2; ++u) {
                const int eidx = j + u * 4 + qg;          // my group's edge
                const bool valid = eidx < m;
                const int bidx = (eidx & 63) * 4;         // bpermute byte idx
                int s = __builtin_amdgcn_ds_bpermute(bidx, px);
                int e = __builtin_amdgcn_ds_bpermute(bidx, py);
                s = valid ? s : NN;                        // zero row
                e = valid ? e : 0;                         // hot row, masked

                const uint4 hv = *(const uint4*)(hb + (size_t)s * INF + ql * 8);
#pragma unroll
                for (int k = 0; k < 4; ++k) {
                    const unsigned w = (&hv.x)[k];
                    union { unsigned u; float f; } lo, hi;
                    lo.u = w << 16;
                    hi.u = w & 0xffff0000u;
                    ax[2 * k]     += lo.f;
                    ax[2 * k + 1] += hi.f;
                }

                const float2v ev = __builtin_nontemporal_load(
                    (const float2v*)(eftr + (size_t)e * EF + ql * 2));
                aex += valid ? ev.x : 0.f;
                aey += valid ? ev.y : 0.f;
            }
        }
    }

    // fold the 4 edge-slot groups: lanes differing in bits 4,5
#pragma unroll
    for (int k = 0; k < 8; ++k) {
        ax[k] += __shfl_xor(ax[k], 16);
        ax[k] += __shfl_xor(ax[k], 32);
    }
    aex += __shfl_xor(aex, 16); aex += __shfl_xor(aex, 32);
    aey += __shfl_xor(aey, 16); aey += __shfl_xor(aey, 32);

    if (qg == 0) {
        const float inv = 1.f / fmaxf((float)(end - start), 1.f);
        ushort8 mv;
#pragma unroll
        for (int k = 0; k < 8; ++k) mv[k] = f2bf(ax[k] * inv);
        *(ushort8*)(mean_h + (size_t)node * INF + ql * 8) = mv;
        const unsigned me =
            (unsigned)f2bf(aex * inv) | ((unsigned)f2bf(aey * inv) << 16);
        *(unsigned*)(mean_e + (size_t)node * EF + ql * 2) = me;
    }
}

// ---------------------------------------------------------------------------
// Node GEMM via MFMA (bf16 in, fp32 acc). LDS-free, barrier-free.
// A operands load directly as bf16 ushort8. out stores nontemporal (write-once).
// ---------------------------------------------------------------------------
__global__ __launch_bounds__(256)
void node_gemm_kernel(const unsigned short* __restrict__ hb,
                      const unsigned short* __restrict__ mean_h,
                      const unsigned short* __restrict__ mean_e,
                      const unsigned short* __restrict__ Mb,
                      const float* __restrict__ cvec,
                      float* __restrict__ out) {
    const int tid = threadIdx.x;
    const int lane = tid & 63;
    const int wid = tid >> 6;
    const int nt = blockIdx.x * 4 + wid;     // 16-node tile id
    const int m16 = lane & 15;
    const int quad = lane >> 4;
    const int koff = quad * 8;

    const int anode = nt * 16 + m16;
    const int nclamp = (anode < NN) ? anode : (NN - 1);

    float4v acc[8] = {};

    for (int kb = 0; kb < 9; ++kb) {
        const unsigned short* srcp;
        if (kb < 4)
            srcp = hb + (size_t)nclamp * INF + kb * 32 + koff;
        else if (kb < 8)
            srcp = mean_h + (size_t)nclamp * INF + (kb - 4) * 32 + koff;
        else
            srcp = mean_e + (size_t)nclamp * EF + koff;
        const short8 a = *(const short8*)(const void*)srcp;

        const short8* bp = (const short8*)(Mb + (size_t)kb * 8 * 64 * 8);
#pragma unroll
        for (int ct = 0; ct < 8; ++ct) {
            const short8 b = bp[ct * 64 + lane];
            acc[ct] = __builtin_amdgcn_mfma_f32_16x16x32_bf16(a, b, acc[ct], 0, 0, 0);
        }
    }

    float cv[8];
#pragma unroll
    for (int ct = 0; ct < 8; ++ct) cv[ct] = cvec[ct * 16 + m16];

#pragma unroll
    for (int r = 0; r < 4; ++r) {
        const int nrow = nt * 16 + quad * 4 + r;
        if (nrow < NN) {
            float* orow = out + (size_t)nrow * OUTF;
#pragma unroll
            for (int ct = 0; ct < 8; ++ct)
                __builtin_nontemporal_store(acc[ct][r] + cv[ct],
                                            &orow[ct * 16 + m16]);
        }
    }
}

extern "C" void kernel_launch(void* const* d_in, const int* in_sizes, int n_in,
                              void* d_out, int out_size, void* d_ws, size_t ws_size,
                              hipStream_t stream) {
    const float* h      = (const float*)d_in[0];
    const float* eftr   = (const float*)d_in[1];
    const float* weight = (const float*)d_in[2];
    const float* W_w    = (const float*)d_in[3];
    const float* W_b    = (const float*)d_in[4];
    const float* bias   = (const float*)d_in[5];
    const int*   src    = (const int*)d_in[6];
    const int*   dst    = (const int*)d_in[7];
    float* out = (float*)d_out;

    // workspace layout (byte offsets):
    char* base = (char*)d_ws;
    unsigned short* mean_h = (unsigned short*)(base);                // NN*128 bf16 = 12,800,000
    unsigned short* mean_e = (unsigned short*)(base + 12800000);     // NN*32  bf16 =  3,200,000
    unsigned short* h_bf   = (unsigned short*)(base + 16000000);     // (NN+1)*128 bf16 = 12,800,256
    float* Mmat            = (float*)(base + 28800512);              // 288*128 f32 = 147,456
    float* cvec            = (float*)(base + 28947968);              // 128 f32 = 512
    unsigned short* Mb     = (unsigned short*)(base + 28948480);     // 73,728
    int*   off             = (int*)(base + 29022208);                // NN int = 200,000
    int2*  eo2             = (int2*)(base + 29222208);               // NE int2 = 6,400,000
    int*   partial         = (int*)(base + 35622208);                // NBLK int
    // total ≈ 35.6 MB

    hipMemsetAsync(off, 0, (size_t)NN * sizeof(int), stream);

    prep_kernel<<<KDIM + 1, 128, 0, stream>>>(weight, W_w, W_b, bias, Mmat, cvec);
    pack_kernel<<<72, 64, 0, stream>>>(Mmat, Mb);
    cvt_hist_kernel<<<CVT_BLKS + 1 + (NE / 4 + 255) / 256, 256, 0, stream>>>(
        h, h_bf, dst, off);
    scan1_kernel<<<NBLK, 256, 0, stream>>>(off, partial);
    scan3_kernel<<<NBLK, 256, 0, stream>>>(off, partial);
    scatter_ids_kernel<<<(NE / 4 + 255) / 256, 256, 0, stream>>>(src, dst, off, eo2);
    gather_kernel<<<(NN + 3) / 4, 256, 0, stream>>>(h_bf, eftr, off, eo2,
                                                    mean_h, mean_e);
    node_gemm_kernel<<<(NN / 64) + 1, 256, 0, stream>>>(h_bf, mean_h, mean_e,
                                                        Mb, cvec, out);
}

// Round 4
// 289.378 us; speedup vs baseline: 1.1779x; 1.1199x over previous
//
#include <hip/hip_runtime.h>

#define NN   50000
#define NE   800000
#define INF  128
#define EF   32
#define OUTF 128
#define KDIM 288   // 128 (h) + 128 (mean_h) + 32 (mean_e)
#define NBLK ((NN + 1023) / 1024)   // 49 scan blocks
#define CVT_BLKS 3125               // NN*INF/2048 exactly

typedef __attribute__((ext_vector_type(8))) short     short8;   // 8 bf16
typedef __attribute__((ext_vector_type(8))) unsigned short ushort8;
typedef __attribute__((ext_vector_type(4))) float     float4v;
typedef __attribute__((ext_vector_type(2))) float     float2v;

__device__ __forceinline__ unsigned short f2bf(float f) {
    union { float f; unsigned int u; } c; c.f = f;
    const unsigned int r = (c.u + 0x7FFFu + ((c.u >> 16) & 1u)) >> 16;
    return (unsigned short)r;
}

// ---------------------------------------------------------------------------
// Prep: build fused matrix M (288x128) fp32 and bias vector c (128).
//   rows 0..127   : M[f][j]     = W_w[j][f]                         (h_dst)
//   rows 128..287 : M[128+m][j] = sum_k weight[m][k]*W_w[j][128+k]  (h_neigh)
//   c[j] = W_b[j] + bias[j]
// ---------------------------------------------------------------------------
__global__ void prep_kernel(const float* __restrict__ weight,
                            const float* __restrict__ W_w,
                            const float* __restrict__ W_b,
                            const float* __restrict__ bias,
                            float* __restrict__ Mmat,
                            float* __restrict__ cvec) {
    __shared__ float wrow[OUTF];
    const int r = blockIdx.x;
    const int j = threadIdx.x;
    if (r < 128) {
        Mmat[r * OUTF + j] = W_w[j * 256 + r];
        return;
    }
    if (r == KDIM) {
        cvec[j] = W_b[j] + bias[j];
        return;
    }
    const int m = r - 128;
    wrow[j] = weight[m * OUTF + j];
    __syncthreads();
    float acc = 0.f;
#pragma unroll 8
    for (int k = 0; k < OUTF; ++k)
        acc += wrow[k] * W_w[j * 256 + 128 + k];
    Mmat[r * OUTF + j] = acc;
}

// ---------------------------------------------------------------------------
// Pack M into bf16 MFMA B-fragment order: Mb[kb(9)][ct(8)][lane(64)][8].
// ---------------------------------------------------------------------------
__global__ void pack_kernel(const float* __restrict__ Mmat,
                            unsigned short* __restrict__ Mb) {
    const int b = blockIdx.x;          // kb*8 + ct
    const int kb = b >> 3;
    const int ct = b & 7;
    const int lane = threadIdx.x;
    const int col = ct * 16 + (lane & 15);
    const int k0 = kb * 32 + (lane >> 4) * 8;
    ushort8 v;
#pragma unroll
    for (int i = 0; i < 8; ++i)
        v[i] = f2bf(Mmat[(size_t)(k0 + i) * OUTF + col]);
    *(ushort8*)(Mb + ((size_t)(b * 64 + lane) * 8)) = v;
}

// ---------------------------------------------------------------------------
// Fused: h fp32->bf16 table (+ zero row NN) and dst histogram.
// Histogram's atomicAdd return value IS the edge's rank within its dst
// bucket -> stored to rank[] so the later scatter needs no atomics.
// Role split by blockIdx: [0,3125)=cvt, 3125=zero row, (3125,..]=hist.
// ---------------------------------------------------------------------------
__global__ __launch_bounds__(256)
void cvt_hist_kernel(const float* __restrict__ h,
                     unsigned short* __restrict__ hb,
                     const int* __restrict__ dst,
                     int* __restrict__ off,
                     int* __restrict__ rank) {
    const int b = blockIdx.x;
    if (b < CVT_BLKS) {
        const size_t i = (size_t)(b * 256 + threadIdx.x) * 8;
        const float4 a0 = *(const float4*)(h + i);
        const float4 a1 = *(const float4*)(h + i + 4);
        ushort8 v;
        v[0] = f2bf(a0.x); v[1] = f2bf(a0.y); v[2] = f2bf(a0.z); v[3] = f2bf(a0.w);
        v[4] = f2bf(a1.x); v[5] = f2bf(a1.y); v[6] = f2bf(a1.z); v[7] = f2bf(a1.w);
        *(ushort8*)(hb + i) = v;
        return;
    }
    if (b == CVT_BLKS) {
        // zero row NN (used as target for masked-off edge slots in gather)
        if (threadIdx.x < 16) {
            ushort8 z = {};
            *(ushort8*)(hb + (size_t)NN * INF + threadIdx.x * 8) = z;
        }
        return;
    }
    const int e = ((b - CVT_BLKS - 1) * 256 + threadIdx.x) * 4;
    if (e < NE) {
        const int4 d = *(const int4*)(dst + e);
        int4 r;
        r.x = atomicAdd(&off[d.x], 1);
        r.y = atomicAdd(&off[d.y], 1);
        r.z = atomicAdd(&off[d.z], 1);
        r.w = atomicAdd(&off[d.w], 1);
        *(int4*)(rank + e) = r;
    }
}

// ---------------------------------------------------------------------------
// Scan phase 1: per-block (1024 elems) sum -> partial[b]
// ---------------------------------------------------------------------------
__global__ __launch_bounds__(256)
void scan1_kernel(const int* __restrict__ off, int* __restrict__ partial) {
    const int b = blockIdx.x;
    const int tid = threadIdx.x;
    const int idx = b * 1024 + tid * 4;
    int v0 = 0, v1 = 0, v2 = 0, v3 = 0;
    if (idx + 3 < NN) {
        const int4 q = *(const int4*)(off + idx);
        v0 = q.x; v1 = q.y; v2 = q.z; v3 = q.w;
    } else {
        if (idx + 0 < NN) v0 = off[idx + 0];
        if (idx + 1 < NN) v1 = off[idx + 1];
        if (idx + 2 < NN) v2 = off[idx + 2];
    }
    int t = v0 + v1 + v2 + v3;
#pragma unroll
    for (int ofs = 32; ofs > 0; ofs >>= 1) t += __shfl_down(t, ofs);
    __shared__ int wsum[4];
    if ((tid & 63) == 0) wsum[tid >> 6] = t;
    __syncthreads();
    if (tid == 0) partial[b] = wsum[0] + wsum[1] + wsum[2] + wsum[3];
}

// ---------------------------------------------------------------------------
// Scan phase 2+3 fused: every block re-scans the 49 partials in one wave,
// then does its local exclusive scan + in-place rewrite of off to EXCLUSIVE
// START offsets. off[NN] = NE sentinel. Scatter no longer mutates off.
// ---------------------------------------------------------------------------
__global__ __launch_bounds__(256)
void scan3_kernel(int* __restrict__ off, const int* __restrict__ partial) {
    __shared__ int blockbase;
    __shared__ int wsum[4];
    const int b = blockIdx.x;
    const int tid = threadIdx.x;
    const int lane = tid & 63;
    const int wid = tid >> 6;

    if (b == 0 && tid == 0) off[NN] = NE;   // sentinel end offset

    if (wid == 0) {
        const int v = (lane < NBLK) ? partial[lane] : 0;
        int x = v;
#pragma unroll
        for (int ofs = 1; ofs < 64; ofs <<= 1) {
            const int t = __shfl_up(x, ofs);
            if (lane >= ofs) x += t;
        }
        if (lane == b) blockbase = x - v;   // exclusive prefix of this block
    }

    const int idx = b * 1024 + tid * 4;
    int v0 = 0, v1 = 0, v2 = 0, v3 = 0;
    if (idx + 3 < NN) {
        const int4 q = *(const int4*)(off + idx);
        v0 = q.x; v1 = q.y; v2 = q.z; v3 = q.w;
    } else {
        if (idx + 0 < NN) v0 = off[idx + 0];
        if (idx + 1 < NN) v1 = off[idx + 1];
        if (idx + 2 < NN) v2 = off[idx + 2];
    }
    const int tsum = v0 + v1 + v2 + v3;
    int x = tsum;
#pragma unroll
    for (int ofs = 1; ofs < 64; ofs <<= 1) {
        const int t = __shfl_up(x, ofs);
        if (lane >= ofs) x += t;
    }
    if (lane == 63) wsum[wid] = x;
    __syncthreads();
    int wp = 0;
    for (int w = 0; w < wid; ++w) wp += wsum[w];
    const int base = blockbase + wp + (x - tsum);
    if (idx + 0 < NN) off[idx + 0] = base;
    if (idx + 1 < NN) off[idx + 1] = base + v0;
    if (idx + 2 < NN) off[idx + 2] = base + v0 + v1;
    if (idx + 3 < NN) off[idx + 3] = base + v0 + v1 + v2;
}

// ---------------------------------------------------------------------------
// CSR build step 3: ATOMIC-FREE scatter. pos = off[d] + rank[e]; the four
// stores per thread are fully independent (no RMW round-trip chains).
// ---------------------------------------------------------------------------
__global__ __launch_bounds__(256)
void scatter_ids_kernel(const int* __restrict__ srcv,
                        const int* __restrict__ dst,
                        const int* __restrict__ off,    // start offsets
                        const int* __restrict__ rank,
                        int2* __restrict__ eo2) {
    const int e = (blockIdx.x * 256 + threadIdx.x) * 4;
    if (e < NE) {
        const int4 s = *(const int4*)(srcv + e);
        const int4 d = *(const int4*)(dst + e);
        const int4 r = *(const int4*)(rank + e);
        eo2[off[d.x] + r.x] = make_int2(s.x, e + 0);
        eo2[off[d.y] + r.y] = make_int2(s.y, e + 1);
        eo2[off[d.z] + r.z] = make_int2(s.z, e + 2);
        eo2[off[d.w] + r.w] = make_int2(s.w, e + 3);
    }
}

// ---------------------------------------------------------------------------
// Gather: one wave per node. Wave is split into four 16-lane groups; each
// group reads one edge's FULL h row (16B/lane dwordx4 = 256B bf16 row) and
// one edge's full eftr row (8B/lane = 128B row). 4 edges per VMEM inst.
// Indices distributed via ds_bpermute; tail slots point at zero-row NN (h) /
// edge 0 with a masked addend (eftr). Partials fold with 2 shfl_xor rounds.
// ---------------------------------------------------------------------------
__global__ __launch_bounds__(256)
void gather_kernel(const unsigned short* __restrict__ hb,
                   const float* __restrict__ eftr,
                   const int* __restrict__ off,   // start offsets, off[NN]=NE
                   const int2* __restrict__ eo2,
                   unsigned short* __restrict__ mean_h,
                   unsigned short* __restrict__ mean_e) {
    const int tid = threadIdx.x;
    const int lane = tid & 63;
    const int node = blockIdx.x * 4 + (tid >> 6);
    if (node >= NN) return;

    const int start = off[node];
    const int end   = off[node + 1];

    const int ql = lane & 15;      // position within 16-lane group
    const int qg = lane >> 4;      // edge-slot group 0..3

    float ax[8] = {0.f, 0.f, 0.f, 0.f, 0.f, 0.f, 0.f, 0.f};
    float aex = 0.f, aey = 0.f;

    for (int base = start; base < end; base += 64) {
        const int m = min(64, end - base);
        int px = 0, py = 0;
        if (lane < m) {
            const long long pv =
                __builtin_nontemporal_load((const long long*)(eo2 + base + lane));
            px = (int)pv;
            py = (int)(pv >> 32);
        }
        for (int j = 0; j < m; j += 8) {
#pragma unroll
            for (int u = 0; u < 2; ++u) {
                const int eidx = j + u * 4 + qg;          // my group's edge
                const bool valid = eidx < m;
                const int bidx = (eidx & 63) * 4;         // bpermute byte idx
                int s = __builtin_amdgcn_ds_bpermute(bidx, px);
                int e = __builtin_amdgcn_ds_bpermute(bidx, py);
                s = valid ? s : NN;                        // zero row
                e = valid ? e : 0;                         // hot row, masked

                const uint4 hv = *(const uint4*)(hb + (size_t)s * INF + ql * 8);
#pragma unroll
                for (int k = 0; k < 4; ++k) {
                    const unsigned w = (&hv.x)[k];
                    union { unsigned u; float f; } lo, hi;
                    lo.u = w << 16;
                    hi.u = w & 0xffff0000u;
                    ax[2 * k]     += lo.f;
                    ax[2 * k + 1] += hi.f;
                }

                const float2v ev = __builtin_nontemporal_load(
                    (const float2v*)(eftr + (size_t)e * EF + ql * 2));
                aex += valid ? ev.x : 0.f;
                aey += valid ? ev.y : 0.f;
            }
        }
    }

    // fold the 4 edge-slot groups: lanes differing in bits 4,5
#pragma unroll
    for (int k = 0; k < 8; ++k) {
        ax[k] += __shfl_xor(ax[k], 16);
        ax[k] += __shfl_xor(ax[k], 32);
    }
    aex += __shfl_xor(aex, 16); aex += __shfl_xor(aex, 32);
    aey += __shfl_xor(aey, 16); aey += __shfl_xor(aey, 32);

    if (qg == 0) {
        const float inv = 1.f / fmaxf((float)(end - start), 1.f);
        ushort8 mv;
#pragma unroll
        for (int k = 0; k < 8; ++k) mv[k] = f2bf(ax[k] * inv);
        *(ushort8*)(mean_h + (size_t)node * INF + ql * 8) = mv;
        const unsigned me =
            (unsigned)f2bf(aex * inv) | ((unsigned)f2bf(aey * inv) << 16);
        *(unsigned*)(mean_e + (size_t)node * EF + ql * 2) = me;
    }
}

// ---------------------------------------------------------------------------
// Node GEMM via MFMA (bf16 in, fp32 acc). LDS-free, barrier-free.
// A operands load directly as bf16 ushort8. out stores nontemporal (write-once).
// ---------------------------------------------------------------------------
__global__ __launch_bounds__(256)
void node_gemm_kernel(const unsigned short* __restrict__ hb,
                      const unsigned short* __restrict__ mean_h,
                      const unsigned short* __restrict__ mean_e,
                      const unsigned short* __restrict__ Mb,
                      const float* __restrict__ cvec,
                      float* __restrict__ out) {
    const int tid = threadIdx.x;
    const int lane = tid & 63;
    const int wid = tid >> 6;
    const int nt = blockIdx.x * 4 + wid;     // 16-node tile id
    const int m16 = lane & 15;
    const int quad = lane >> 4;
    const int koff = quad * 8;

    const int anode = nt * 16 + m16;
    const int nclamp = (anode < NN) ? anode : (NN - 1);

    float4v acc[8] = {};

    for (int kb = 0; kb < 9; ++kb) {
        const unsigned short* srcp;
        if (kb < 4)
            srcp = hb + (size_t)nclamp * INF + kb * 32 + koff;
        else if (kb < 8)
            srcp = mean_h + (size_t)nclamp * INF + (kb - 4) * 32 + koff;
        else
            srcp = mean_e + (size_t)nclamp * EF + koff;
        const short8 a = *(const short8*)(const void*)srcp;

        const short8* bp = (const short8*)(Mb + (size_t)kb * 8 * 64 * 8);
#pragma unroll
        for (int ct = 0; ct < 8; ++ct) {
            const short8 b = bp[ct * 64 + lane];
            acc[ct] = __builtin_amdgcn_mfma_f32_16x16x32_bf16(a, b, acc[ct], 0, 0, 0);
        }
    }

    float cv[8];
#pragma unroll
    for (int ct = 0; ct < 8; ++ct) cv[ct] = cvec[ct * 16 + m16];

#pragma unroll
    for (int r = 0; r < 4; ++r) {
        const int nrow = nt * 16 + quad * 4 + r;
        if (nrow < NN) {
            float* orow = out + (size_t)nrow * OUTF;
#pragma unroll
            for (int ct = 0; ct < 8; ++ct)
                __builtin_nontemporal_store(acc[ct][r] + cv[ct],
                                            &orow[ct * 16 + m16]);
        }
    }
}

extern "C" void kernel_launch(void* const* d_in, const int* in_sizes, int n_in,
                              void* d_out, int out_size, void* d_ws, size_t ws_size,
                              hipStream_t stream) {
    const float* h      = (const float*)d_in[0];
    const float* eftr   = (const float*)d_in[1];
    const float* weight = (const float*)d_in[2];
    const float* W_w    = (const float*)d_in[3];
    const float* W_b    = (const float*)d_in[4];
    const float* bias   = (const float*)d_in[5];
    const int*   src    = (const int*)d_in[6];
    const int*   dst    = (const int*)d_in[7];
    float* out = (float*)d_out;

    // workspace layout (byte offsets):
    char* base = (char*)d_ws;
    unsigned short* mean_h = (unsigned short*)(base);                // NN*128 bf16 = 12,800,000
    unsigned short* mean_e = (unsigned short*)(base + 12800000);     // NN*32  bf16 =  3,200,000
    unsigned short* h_bf   = (unsigned short*)(base + 16000000);     // (NN+1)*128 bf16 = 12,800,256
    float* Mmat            = (float*)(base + 28800512);              // 288*128 f32 = 147,456
    float* cvec            = (float*)(base + 28947968);              // 128 f32 = 512
    unsigned short* Mb     = (unsigned short*)(base + 28948480);     // 73,728
    int*   off             = (int*)(base + 29022208);                // (NN+1) int = 200,004 (+pad)
    int2*  eo2             = (int2*)(base + 29222912);               // NE int2 = 6,400,000
    int*   rank            = (int*)(base + 35622912);                // NE int = 3,200,000
    int*   partial         = (int*)(base + 38822912);                // NBLK int
    // total ≈ 38.8 MB

    hipMemsetAsync(off, 0, (size_t)NN * sizeof(int), stream);

    prep_kernel<<<KDIM + 1, 128, 0, stream>>>(weight, W_w, W_b, bias, Mmat, cvec);
    pack_kernel<<<72, 64, 0, stream>>>(Mmat, Mb);
    cvt_hist_kernel<<<CVT_BLKS + 1 + (NE / 4 + 255) / 256, 256, 0, stream>>>(
        h, h_bf, dst, off, rank);
    scan1_kernel<<<NBLK, 256, 0, stream>>>(off, partial);
    scan3_kernel<<<NBLK, 256, 0, stream>>>(off, partial);
    scatter_ids_kernel<<<(NE / 4 + 255) / 256, 256, 0, stream>>>(src, dst, off,
                                                                 rank, eo2);
    gather_kernel<<<(NN + 3) / 4, 256, 0, stream>>>(h_bf, eftr, off, eo2,
                                                    mean_h, mean_e);
    node_gemm_kernel<<<(NN / 64) + 1, 256, 0, stream>>>(h_bf, mean_h, mean_e,
                                                        Mb, cvec, out);
}